// Round 1
// baseline (145.287 us; speedup 1.0000x reference)
//
#include <hip/hip_runtime.h>
#include <stdint.h>

// Problem constants (fixed by the reference: B=2048, K=6144, MU=2,
// G0 = 1 + D^2 (feedback), G1 = 1 + D + D^2 (parity)).
#define KLEN  6144
#define BROWS 2048
#define NG    (BROWS / 32)      // 64 bit-groups of 32 rows
#define GK    (NG * KLEN)       // u32 words per packed plane = 393216
#define NCH   48                // chunks per row for parallel scan
#define CHLEN (KLEN / NCH)      // 128 (EVEN — required so M^CHLEN == I)

// RSC recursion (bitwise over 32 rows packed in a u32):
//   fb  = u ^ s1
//   par = fb ^ s0 ^ s1 = u ^ s0
//   (s0, s1) <- (fb, s0)
// Linear part of the state map is the swap matrix M; M^2 = I, so for an
// even-length chunk:  s_end_actual = s_end_zeroinit ^ s_start_actual.

// ---------------------------------------------------------------------------
// Kernel A: bit-pack bits[B][K] (float 0/1) -> packedS[g*K + t], bit j = row g*32+j.
// Thread = (g, t); reads are coalesced over t (64 consecutive floats per wave
// per j-iteration), each element read exactly once.
__global__ void pack_kernel(const float* __restrict__ bits,
                            uint32_t* __restrict__ packedS) {
    int tid = blockIdx.x * blockDim.x + threadIdx.x;   // [0, NG*KLEN)
    int g = tid / KLEN;
    int t = tid - g * KLEN;
    const float* rowbase = bits + (size_t)(g * 32) * KLEN + t;
    uint32_t w = 0;
#pragma unroll
    for (int j = 0; j < 32; ++j) {
        float f = rowbase[(size_t)j * KLEN];
        w |= (f > 0.5f ? 1u : 0u) << j;
    }
    packedS[tid] = w;
}

// ---------------------------------------------------------------------------
// Kernel B1: per (enc, g, chunk) zero-init scan -> chunk end states.
__global__ void chunk_ends_kernel(const uint32_t* __restrict__ packedS,
                                  const int* __restrict__ perm,
                                  uint32_t* __restrict__ ends) {
    int tid = blockIdx.x * blockDim.x + threadIdx.x;   // [0, 2*NG*NCH)
    int enc = tid / (NG * NCH);
    int r   = tid - enc * (NG * NCH);
    int g   = r / NCH;
    int c   = r - g * NCH;

    const uint32_t* base = packedS + g * KLEN;
    uint32_t s0 = 0, s1 = 0;
    int t0 = c * CHLEN;
    for (int tau = 0; tau < CHLEN; ++tau) {
        int t = t0 + tau;
        int idx = enc ? perm[t] : t;
        uint32_t u = base[idx];
        uint32_t ns0 = u ^ s1;   // fb
        s1 = s0;
        s0 = ns0;
    }
    ends[2 * tid + 0] = s0;
    ends[2 * tid + 1] = s1;
}

// ---------------------------------------------------------------------------
// Kernel B2: per (enc, g, chunk): init = XOR of previous chunks' zero-ends
// (valid because M^CHLEN = I), then rescan emitting packed parities.
__global__ void parity_kernel(const uint32_t* __restrict__ packedS,
                              const int* __restrict__ perm,
                              const uint32_t* __restrict__ ends,
                              uint32_t* __restrict__ p1,
                              uint32_t* __restrict__ p2) {
    int tid = blockIdx.x * blockDim.x + threadIdx.x;   // [0, 2*NG*NCH)
    int enc = tid / (NG * NCH);
    int r   = tid - enc * (NG * NCH);
    int g   = r / NCH;
    int c   = r - g * NCH;

    // XOR-prefix of zero-init end states of preceding chunks = actual init.
    uint32_t s0 = 0, s1 = 0;
    int ebase = (enc * NG + g) * NCH;
    for (int cc = 0; cc < c; ++cc) {
        s0 ^= ends[2 * (ebase + cc) + 0];
        s1 ^= ends[2 * (ebase + cc) + 1];
    }

    uint32_t* __restrict__ pout = enc ? p2 : p1;
    const uint32_t* base = packedS + g * KLEN;
    int t0 = c * CHLEN;
    for (int tau = 0; tau < CHLEN; ++tau) {
        int t = t0 + tau;
        int idx = enc ? perm[t] : t;
        uint32_t u = base[idx];
        pout[g * KLEN + t] = u ^ s0;   // parity = u XOR state0 (pre-update)
        uint32_t ns0 = u ^ s1;
        s1 = s0;
        s0 = ns0;
    }
}

// ---------------------------------------------------------------------------
// Kernel C: emit interleaved codeword [sys, p1, p2] per time step as float.
// Thread = (b, t-quad): 3 uint4 loads (L1/L2-resident packed planes),
// 3 contiguous float4 stores -> 151 MB fully-coalesced write.
__global__ void emit_kernel(const uint32_t* __restrict__ ps,
                            const uint32_t* __restrict__ p1,
                            const uint32_t* __restrict__ p2,
                            float* __restrict__ out) {
    int tid = blockIdx.x * blockDim.x + threadIdx.x;   // [0, BROWS*KLEN/4)
    int b = tid / (KLEN / 4);
    int q = tid - b * (KLEN / 4);
    int t0 = q * 4;
    int g = b >> 5;
    int bit = b & 31;

    size_t wbase = (size_t)g * KLEN + t0;
    uint4 ws = *(const uint4*)(ps + wbase);
    uint4 w1 = *(const uint4*)(p1 + wbase);
    uint4 w2 = *(const uint4*)(p2 + wbase);

    float4 f0, f1, f2;
    f0.x = (float)((ws.x >> bit) & 1u);
    f0.y = (float)((w1.x >> bit) & 1u);
    f0.z = (float)((w2.x >> bit) & 1u);
    f0.w = (float)((ws.y >> bit) & 1u);
    f1.x = (float)((w1.y >> bit) & 1u);
    f1.y = (float)((w2.y >> bit) & 1u);
    f1.z = (float)((ws.z >> bit) & 1u);
    f1.w = (float)((w1.z >> bit) & 1u);
    f2.x = (float)((w2.z >> bit) & 1u);
    f2.y = (float)((ws.w >> bit) & 1u);
    f2.z = (float)((w1.w >> bit) & 1u);
    f2.w = (float)((w2.w >> bit) & 1u);

    float4* o = (float4*)(out + (size_t)b * (3 * KLEN) + (size_t)t0 * 3);
    o[0] = f0;
    o[1] = f1;
    o[2] = f2;
}

// ---------------------------------------------------------------------------
extern "C" void kernel_launch(void* const* d_in, const int* in_sizes, int n_in,
                              void* d_out, int out_size, void* d_ws, size_t ws_size,
                              hipStream_t stream) {
    const float* bits = (const float*)d_in[0];   // [B*K] float 0/1
    const int*   perm = (const int*)d_in[1];     // [K] int32
    float* out = (float*)d_out;                  // [B * 3K] float

    uint32_t* ws = (uint32_t*)d_ws;
    uint32_t* packedS = ws;                      // [GK]
    uint32_t* p1      = ws + (size_t)GK;         // [GK]
    uint32_t* p2      = ws + (size_t)2 * GK;     // [GK]
    uint32_t* ends    = ws + (size_t)3 * GK;     // [2*NG*NCH*2]

    hipLaunchKernelGGL(pack_kernel, dim3(GK / 256), dim3(256), 0, stream,
                       bits, packedS);
    hipLaunchKernelGGL(chunk_ends_kernel, dim3((2 * NG * NCH) / 256), dim3(256), 0, stream,
                       packedS, perm, ends);
    hipLaunchKernelGGL(parity_kernel, dim3((2 * NG * NCH) / 256), dim3(256), 0, stream,
                       packedS, perm, ends, p1, p2);
    hipLaunchKernelGGL(emit_kernel, dim3((BROWS * (KLEN / 4)) / 256), dim3(256), 0, stream,
                       packedS, p1, p2, out);
}

// Round 2
// 59.183 us; speedup vs baseline: 2.4549x; 2.4549x over previous
//
#include <hip/hip_runtime.h>
#include <stdint.h>

// Problem constants (fixed by the reference: B=2048, K=6144, MU=2,
// G0 = 1 + D^2 (feedback), G1 = 1 + D + D^2 (parity)).
#define KLEN  6144
#define BROWS 2048
#define NG    (BROWS / 32)      // 64 bit-groups of 32 rows
#define GK    (NG * KLEN)       // u32 words per packed plane = 393216
#define NT    256               // threads per scan block (= chunks per row)
#define CL    (KLEN / NT)       // 24 — EVEN, required so M^CL == I

// RSC recursion (bitwise over 32 rows packed in a u32):
//   fb  = u ^ s1
//   par = fb ^ s0 ^ s1 = u ^ s0
//   (s0, s1) <- (fb, s0)
// Linear part of the state map is the swap matrix M; M^2 = I, so for an
// even-length chunk: s_end_actual = s_end_zeroinit ^ s_start_actual, and the
// actual init of chunk c is the XOR of all preceding chunks' zero-init ends.

// ---------------------------------------------------------------------------
// Kernel A: bit-pack bits[B][K] (float 0/1) -> packedS[g*K + t], bit j = row g*32+j.
// Thread = (g, t); reads are coalesced over t (256 B per wave per j-iter),
// each input element read exactly once.
__global__ void pack_kernel(const float* __restrict__ bits,
                            uint32_t* __restrict__ packedS) {
    int tid = blockIdx.x * blockDim.x + threadIdx.x;   // [0, NG*KLEN)
    int g = tid / KLEN;
    int t = tid - g * KLEN;
    const float* rowbase = bits + (size_t)(g * 32) * KLEN + t;
    uint32_t w = 0;
#pragma unroll
    for (int j = 0; j < 32; ++j) {
        float f = rowbase[(size_t)j * KLEN];
        w |= (f > 0.5f ? 1u : 0u) << j;
    }
    packedS[tid] = w;
}

// ---------------------------------------------------------------------------
// Kernel B (fused scan): one workgroup per (enc, g). Thread c owns chunk c
// (CL=24 steps). Phase 1: zero-init scan -> end state. Phase 2: block-wide
// XOR prefix (Hillis-Steele in LDS). Phase 3: rescan from corrected init
// using register-cached u[], emit packed parities as 6 aligned uint4 stores.
__global__ __launch_bounds__(NT) void scan_kernel(
        const uint32_t* __restrict__ packedS,
        const int* __restrict__ perm,
        uint32_t* __restrict__ p1,
        uint32_t* __restrict__ p2) {
    int c = threadIdx.x;
    int enc = blockIdx.x >> 6;        // 0 or 1
    int g   = blockIdx.x & (NG - 1);

    const uint32_t* base = packedS + g * KLEN;
    int t0 = c * CL;

    // Load this chunk's inputs into registers (gathered via perm for enc 1).
    uint32_t u[CL];
    if (enc) {
#pragma unroll
        for (int i = 0; i < CL; ++i) u[i] = base[perm[t0 + i]];
    } else {
#pragma unroll
        for (int i = 0; i < CL; ++i) u[i] = base[t0 + i];
    }

    // Phase 1: zero-init chunk scan -> end state (s0,s1).
    uint32_t s0 = 0, s1 = 0;
#pragma unroll
    for (int i = 0; i < CL; ++i) { uint32_t ns0 = u[i] ^ s1; s1 = s0; s0 = ns0; }

    // Phase 2: inclusive XOR prefix over threads, then take exclusive.
    __shared__ uint32_t a0[NT], a1[NT];
    a0[c] = s0; a1[c] = s1;
    __syncthreads();
#pragma unroll
    for (int off = 1; off < NT; off <<= 1) {
        uint32_t x0 = 0, x1 = 0;
        if (c >= off) { x0 = a0[c - off]; x1 = a1[c - off]; }
        __syncthreads();
        a0[c] ^= x0; a1[c] ^= x1;
        __syncthreads();
    }
    s0 = c ? a0[c - 1] : 0u;
    s1 = c ? a1[c - 1] : 0u;

    // Phase 3: rescan with actual init, emit parities.
    uint32_t p[CL];
#pragma unroll
    for (int i = 0; i < CL; ++i) {
        p[i] = u[i] ^ s0;                 // parity = u XOR state0 (pre-update)
        uint32_t ns0 = u[i] ^ s1; s1 = s0; s0 = ns0;
    }

    uint32_t* __restrict__ pout = enc ? p2 : p1;
    uint4* dst = (uint4*)(pout + g * KLEN + t0);   // t0*4 bytes = 96c: 16B-aligned
#pragma unroll
    for (int i = 0; i < CL / 4; ++i)
        dst[i] = make_uint4(p[4 * i], p[4 * i + 1], p[4 * i + 2], p[4 * i + 3]);
}

// ---------------------------------------------------------------------------
// Kernel C: emit interleaved codeword [sys, p1, p2] per time step as float.
// Thread = (b, t-quad): 3 uint4 loads (L2-resident packed planes),
// 3 contiguous float4 stores -> 151 MB fully-coalesced write.
__global__ void emit_kernel(const uint32_t* __restrict__ ps,
                            const uint32_t* __restrict__ p1,
                            const uint32_t* __restrict__ p2,
                            float* __restrict__ out) {
    int tid = blockIdx.x * blockDim.x + threadIdx.x;   // [0, BROWS*KLEN/4)
    int b = tid / (KLEN / 4);
    int q = tid - b * (KLEN / 4);
    int t0 = q * 4;
    int g = b >> 5;
    int bit = b & 31;

    size_t wbase = (size_t)g * KLEN + t0;
    uint4 ws = *(const uint4*)(ps + wbase);
    uint4 w1 = *(const uint4*)(p1 + wbase);
    uint4 w2 = *(const uint4*)(p2 + wbase);

    float4 f0, f1, f2;
    f0.x = (float)((ws.x >> bit) & 1u);
    f0.y = (float)((w1.x >> bit) & 1u);
    f0.z = (float)((w2.x >> bit) & 1u);
    f0.w = (float)((ws.y >> bit) & 1u);
    f1.x = (float)((w1.y >> bit) & 1u);
    f1.y = (float)((w2.y >> bit) & 1u);
    f1.z = (float)((ws.z >> bit) & 1u);
    f1.w = (float)((w1.z >> bit) & 1u);
    f2.x = (float)((w2.z >> bit) & 1u);
    f2.y = (float)((ws.w >> bit) & 1u);
    f2.z = (float)((w1.w >> bit) & 1u);
    f2.w = (float)((w2.w >> bit) & 1u);

    float4* o = (float4*)(out + (size_t)b * (3 * KLEN) + (size_t)t0 * 3);
    o[0] = f0;
    o[1] = f1;
    o[2] = f2;
}

// ---------------------------------------------------------------------------
extern "C" void kernel_launch(void* const* d_in, const int* in_sizes, int n_in,
                              void* d_out, int out_size, void* d_ws, size_t ws_size,
                              hipStream_t stream) {
    const float* bits = (const float*)d_in[0];   // [B*K] float 0/1
    const int*   perm = (const int*)d_in[1];     // [K] int32
    float* out = (float*)d_out;                  // [B * 3K] float

    uint32_t* ws = (uint32_t*)d_ws;
    uint32_t* packedS = ws;                      // [GK]
    uint32_t* p1      = ws + (size_t)GK;         // [GK]
    uint32_t* p2      = ws + (size_t)2 * GK;     // [GK]

    hipLaunchKernelGGL(pack_kernel, dim3(GK / 256), dim3(256), 0, stream,
                       bits, packedS);
    hipLaunchKernelGGL(scan_kernel, dim3(2 * NG), dim3(NT), 0, stream,
                       packedS, perm, p1, p2);
    hipLaunchKernelGGL(emit_kernel, dim3((BROWS * (KLEN / 4)) / 256), dim3(256), 0, stream,
                       packedS, p1, p2, out);
}